// Round 10
// baseline (1265.938 us; speedup 1.0000x reference)
//
#include <hip/hip_runtime.h>
#include <stdint.h>

#define Mdim 8192
#define Ndim 4096
#define Kdim 2048
#define Hdim 1024

typedef __attribute__((ext_vector_type(8))) short bf16x8;
typedef __attribute__((ext_vector_type(4))) float f32x4;

__device__ __forceinline__ unsigned short f2bf(float f) {
  union { float f; unsigned u; } v; v.f = f;
  unsigned u = v.u + 0x7fffu + ((v.u >> 16) & 1u);
  return (unsigned short)(u >> 16);
}
__device__ __forceinline__ float bf2f(unsigned short s) {
  union { unsigned u; float f; } v; v.u = ((unsigned)s) << 16;
  return v.f;
}
__device__ __forceinline__ float sigmoidf_(float x) { return 1.f / (1.f + __expf(-x)); }
__device__ __forceinline__ float tanhf_(float x) { return 1.f - 2.f / (1.f + __expf(2.f * x)); }

// ---------- fused pack: [x|h] -> bf16 A[M][K]  and  [Wxh;Whh]^T -> bf16 Wt[N][K] ----------
__global__ void pack_kernel(const float* __restrict__ x, const float* __restrict__ h,
                            const float* __restrict__ Wxh, const float* __restrict__ Whh,
                            unsigned short* __restrict__ A, unsigned short* __restrict__ Wt) {
  if (blockIdx.x < 8192) {
    int idx = blockIdx.x * 256 + threadIdx.x;
    int m = idx >> 8;
    int k = (idx & 255) * 8;
    const float* src = (k < Hdim) ? (x + (size_t)m * Hdim + k)
                                  : (h + (size_t)m * Hdim + (k - Hdim));
    float4 a = ((const float4*)src)[0];
    float4 b = ((const float4*)src)[1];
    union { unsigned short s[8]; int4 v; } o;
    o.s[0] = f2bf(a.x); o.s[1] = f2bf(a.y); o.s[2] = f2bf(a.z); o.s[3] = f2bf(a.w);
    o.s[4] = f2bf(b.x); o.s[5] = f2bf(b.y); o.s[6] = f2bf(b.z); o.s[7] = f2bf(b.w);
    *(int4*)(A + (size_t)idx * 8) = o.v;
    return;
  }
  __shared__ float tile[32][33];
  int b2 = blockIdx.x - 8192;
  int k0 = (b2 & 63) * 32;
  int n0 = (b2 >> 6) * 32;
  int tx = threadIdx.x & 31, ty = threadIdx.x >> 5;  // 32 x 8
#pragma unroll
  for (int i = 0; i < 32; i += 8) {
    int k = k0 + ty + i;
    float v = (k < Hdim) ? Wxh[(size_t)k * Ndim + n0 + tx]
                         : Whh[(size_t)(k - Hdim) * Ndim + n0 + tx];
    tile[ty + i][tx] = v;
  }
  __syncthreads();
#pragma unroll
  for (int i = 0; i < 32; i += 8) {
    int n = n0 + ty + i;
    Wt[(size_t)n * Kdim + k0 + tx] = f2bf(tile[tx][ty + i]);
  }
}

// ---------- GEMM: C[M][N] (bf16) = A[M][K] * Wt[N][K]^T ----------
// v10: BK 64->32 => LDS 128KB->64KB => TWO blocks/CU (was one). R9 showed the
// remaining stall is intra-block convoy at barriers with nothing else resident;
// m114-style cross-block overlap needs a second block. Same v9 schedule (one
// barrier/phase, R1 stage placement, counted vmcnt). Swizzle: 4 slots/row now;
// ^(row&3) is a 4-way conflict (R0 measured 1.7e7) — use slot^((row>>1)&3):
// 16 lanes spread over 8 distinct 4-bank groups = 2-way = free (m136).
// launch_bounds(512,4) caps VGPR at 128 so 2 blocks (16 waves/CU) fit.
#define BM 256
#define BN 256
#define BK 32
#define NT (Kdim / BK)   // 64

#define LGKM0_SB() do {                                              \
    asm volatile("s_waitcnt lgkmcnt(0)" ::: "memory");               \
    __builtin_amdgcn_sched_barrier(0);                               \
  } while (0)

__global__ __launch_bounds__(512, 4)
void gemm_kernel(const unsigned short* __restrict__ A, const unsigned short* __restrict__ Bt,
                 unsigned short* __restrict__ C) {
  __shared__ unsigned short lds[2][2][BM * BK];   // 64 KiB
  const int tid = threadIdx.x;
  int bid = blockIdx.x;
  int id = (bid & 7) * 64 + (bid >> 3);      // XCD swizzle (512 % 8 == 0, bijective)
  int mT = id >> 4, nT = id & 15;            // 32 x 16 tiles
  size_t m0 = (size_t)mT * BM, n0 = (size_t)nT * BN;
  const int lane = tid & 63, w = tid >> 6;
  const int wm = w >> 2, wn = w & 3;         // 2x4 waves -> 128x64 output each
  const int r16 = lane & 15, q = lane >> 4;  // q in 0..3 = k-slot (and D row nibble)

  const unsigned short* gA = A + m0 * Kdim;
  const unsigned short* gB = Bt + n0 * Kdim;

  // stage one half-tile (region: 0=A rows0-127, 1=A rows128-255, 2=B0, 3=B1).
  // One 16B gload per thread (512 x 16B = 8KB = 128 rows x 32 bf16).
  // LDS dest linear; slot swizzle stored_slot = logical ^ ((row>>1)&3) applied
  // on the GLOBAL source (rule #21).
  auto stage = [&](int b, int kt, int region) {
    const int mat = region >> 1, half = region & 1;
    const unsigned short* g = mat ? gB : gA;
    int rr = tid >> 2, ss = tid & 3;
    __builtin_amdgcn_global_load_lds(
        (const __attribute__((address_space(1))) void*)(
            g + (size_t)(half * 128 + rr) * Kdim + kt * BK + ((ss ^ ((rr >> 1) & 3)) << 3)),
        (__attribute__((address_space(3))) void*)(&lds[b][mat][half * (128 * BK) + tid * 8]),
        16, 0, 0);
  };

  f32x4 acc[8][4] = {};
  bf16x8 av0[4], av1[4], bv0[2], bv1[2];

  auto readA = [&](int cur, int mh, bf16x8 (&av)[4]) {
#pragma unroll
    for (int mi = 0; mi < 4; ++mi) {
      int lr = wm * 128 + mh * 64 + mi * 16 + r16;
      av[mi] = *(const bf16x8*)(&lds[cur][0][lr * BK + ((q ^ ((lr >> 1) & 3)) << 3)]);
    }
  };
  auto readB = [&](int cur, int nh, bf16x8 (&bv)[2]) {
#pragma unroll
    for (int ni = 0; ni < 2; ++ni) {
      int lr = wn * 64 + nh * 32 + ni * 16 + r16;
      bv[ni] = *(const bf16x8*)(&lds[cur][1][lr * BK + ((q ^ ((lr >> 1) & 3)) << 3)]);
    }
  };

#define QUAD(AV, BV, MI0, NI0)                                                        \
  do {                                                                                \
    __builtin_amdgcn_s_setprio(1);                                                    \
    _Pragma("unroll") for (int mi = 0; mi < 4; ++mi)                                  \
      _Pragma("unroll") for (int ni = 0; ni < 2; ++ni)                                \
        acc[(MI0) + mi][(NI0) + ni] = __builtin_amdgcn_mfma_f32_16x16x32_bf16(        \
            AV[mi], BV[ni], acc[(MI0) + mi][(NI0) + ni], 0, 0, 0);                    \
    __builtin_amdgcn_s_setprio(0);                                                    \
  } while (0)

  // prologue: 6 regions in flight (1 op each); vmcnt(2) -> tile0 resident,
  // {A0(1),A1(1)} in flight. Loop invariant entering iter t: tile t resident;
  // in-flight = {A0(t+1), A1(t+1)} (2 ops).
  stage(0, 0, 0); stage(0, 0, 1); stage(0, 0, 2); stage(0, 0, 3);
  stage(1, 1, 0); stage(1, 1, 1);
  asm volatile("s_waitcnt vmcnt(2)" ::: "memory");
  __builtin_amdgcn_s_barrier();

  // main loop: one barrier per phase (v9 WAR derivation unchanged; region
  // staleness in phases identical).
#pragma unroll 1
  for (int t = 0; t < NT - 2; ++t) {
    int cur = t & 1, nxt = cur ^ 1;
    // P1: reads av0+bv0 (6); stage B0(t+1)
    readA(cur, 0, av0);
    readB(cur, 0, bv0);
    stage(nxt, t + 1, 2);
    __builtin_amdgcn_s_barrier();
    LGKM0_SB();
    QUAD(av0, bv0, 0, 0);
    // P2: reads av1 (4); stage B1(t+1)
    readA(cur, 1, av1);
    stage(nxt, t + 1, 3);
    __builtin_amdgcn_s_barrier();
    LGKM0_SB();
    QUAD(av1, bv0, 4, 0);
    // P3: reads bv1 (2); stage A0(t+2) AFTER barrier (A0(cur) last read @P1)
    readB(cur, 1, bv1);
    __builtin_amdgcn_s_barrier();
    LGKM0_SB();
    stage(cur, t + 2, 0);
    QUAD(av1, bv1, 4, 2);
    // P4: stage A1(t+2); vmcnt(2) retires tile t+1's 4 regions,
    // leaves {A0,A1(t+2)}
    stage(cur, t + 2, 1);
    asm volatile("s_waitcnt vmcnt(2)" ::: "memory");
    __builtin_amdgcn_s_barrier();
    LGKM0_SB();
    QUAD(av0, bv1, 0, 2);
  }
  // t = NT-2: stage B(NT-1) at P1/P2; full drain before last K-tile
  {
    const int cur = (NT - 2) & 1, nxt = cur ^ 1;
    readA(cur, 0, av0);
    readB(cur, 0, bv0);
    stage(nxt, NT - 1, 2);
    __builtin_amdgcn_s_barrier();
    LGKM0_SB();
    QUAD(av0, bv0, 0, 0);
    readA(cur, 1, av1);
    stage(nxt, NT - 1, 3);
    __builtin_amdgcn_s_barrier();
    LGKM0_SB();
    QUAD(av1, bv0, 4, 0);
    readB(cur, 1, bv1);
    __builtin_amdgcn_s_barrier();
    LGKM0_SB();
    QUAD(av1, bv1, 4, 2);
    asm volatile("s_waitcnt vmcnt(0)" ::: "memory");
    __builtin_amdgcn_s_barrier();
    LGKM0_SB();
    QUAD(av0, bv1, 0, 2);
  }
  // t = NT-1: all resident, no stages -> dependency-ordered only
  {
    const int cur = (NT - 1) & 1;
    readA(cur, 0, av0);
    readB(cur, 0, bv0);
    QUAD(av0, bv0, 0, 0);
    readA(cur, 1, av1);
    QUAD(av1, bv0, 4, 0);
    readB(cur, 1, bv1);
    QUAD(av1, bv1, 4, 2);
    QUAD(av0, bv1, 0, 2);
  }
#undef QUAD

  // epilogue: D layout col = lane&15, row = (lane>>4)*4 + j
#pragma unroll
  for (int mi = 0; mi < 8; ++mi) {
#pragma unroll
    for (int ni = 0; ni < 4; ++ni) {
      size_t row = m0 + wm * 128 + mi * 16 + q * 4;
      size_t col = n0 + wn * 64 + ni * 16 + r16;
#pragma unroll
      for (int j = 0; j < 4; ++j)
        C[(row + j) * Ndim + col] = f2bf(acc[mi][ni][j]);
    }
  }
}

// ---------- tail: bias + group LN + gates + c LN + outputs ----------
// v10: parameter loads (bias/gamma/beta/cg/cb) vectorized float4 (were 192
// scalar dword loads per thread -> 48 float4), short live ranges.
__global__ __launch_bounds__(256)
void tail_kernel(const unsigned short* __restrict__ Cc, const float* __restrict__ cin,
                 const float* __restrict__ bias, const float* __restrict__ gamma,
                 const float* __restrict__ beta, const float* __restrict__ cg,
                 const float* __restrict__ cb, float* __restrict__ out) {
  int lane = threadIdx.x & 63;
  int wid = threadIdx.x >> 6;
  int row = blockIdx.x * 4 + wid;     // one wave per row
  const int base = lane * 16;         // 16 columns per lane

  const float4* cp = (const float4*)(cin + (size_t)row * Hdim + base);
  float4 c0 = cp[0], c1 = cp[1], c2 = cp[2], c3 = cp[3];
  float cv[16] = {c0.x, c0.y, c0.z, c0.w, c1.x, c1.y, c1.z, c1.w,
                  c2.x, c2.y, c2.z, c2.w, c3.x, c3.y, c3.z, c3.w};

  float accv[16];   // running sig(i)*tanh(j), then new_c
  float ov[16];     // sig(o)

#pragma unroll
  for (int g = 0; g < 4; ++g) {
    const int4* pp = (const int4*)(Cc + (size_t)row * Ndim + g * Hdim + base);
    int4 u0 = pp[0], u1 = pp[1];
    float vals[16];
    {
      int uu[8] = {u0.x, u0.y, u0.z, u0.w, u1.x, u1.y, u1.z, u1.w};
#pragma unroll
      for (int i = 0; i < 8; ++i) {
        vals[2 * i]     = bf2f((unsigned short)(uu[i] & 0xffff));
        vals[2 * i + 1] = bf2f((unsigned short)(((unsigned)uu[i]) >> 16));
      }
    }
    const float4* bp4 = (const float4*)(bias + g * Hdim + base);
#pragma unroll
    for (int v = 0; v < 4; ++v) {
      float4 b4 = bp4[v];
      vals[4 * v]     += b4.x;
      vals[4 * v + 1] += b4.y;
      vals[4 * v + 2] += b4.z;
      vals[4 * v + 3] += b4.w;
    }
    float s = 0.f, ss = 0.f;
#pragma unroll
    for (int t = 0; t < 16; ++t) { s += vals[t]; ss += vals[t] * vals[t]; }
#pragma unroll
    for (int off = 32; off; off >>= 1) { s += __shfl_xor(s, off); ss += __shfl_xor(ss, off); }
    float mean = s * (1.f / 1024.f);
    float rstd = rsqrtf(ss * (1.f / 1024.f) - mean * mean + 1e-3f);
    const float4* gp4 = (const float4*)(gamma + g * Hdim + base);
    const float4* bb4 = (const float4*)(beta + g * Hdim + base);
#pragma unroll
    for (int v = 0; v < 4; ++v) {
      float4 g4 = gp4[v], e4 = bb4[v];
      float n0_ = (vals[4 * v]     - mean) * rstd * g4.x + e4.x;
      float n1_ = (vals[4 * v + 1] - mean) * rstd * g4.y + e4.y;
      float n2_ = (vals[4 * v + 2] - mean) * rstd * g4.z + e4.z;
      float n3_ = (vals[4 * v + 3] - mean) * rstd * g4.w + e4.w;
      if (g == 0) {
        accv[4 * v] = sigmoidf_(n0_); accv[4 * v + 1] = sigmoidf_(n1_);
        accv[4 * v + 2] = sigmoidf_(n2_); accv[4 * v + 3] = sigmoidf_(n3_);
      } else if (g == 1) {
        accv[4 * v] *= tanhf_(n0_); accv[4 * v + 1] *= tanhf_(n1_);
        accv[4 * v + 2] *= tanhf_(n2_); accv[4 * v + 3] *= tanhf_(n3_);
      } else if (g == 2) {
        accv[4 * v]     = cv[4 * v]     * sigmoidf_(n0_ + 1.f) + accv[4 * v];
        accv[4 * v + 1] = cv[4 * v + 1] * sigmoidf_(n1_ + 1.f) + accv[4 * v + 1];
        accv[4 * v + 2] = cv[4 * v + 2] * sigmoidf_(n2_ + 1.f) + accv[4 * v + 2];
        accv[4 * v + 3] = cv[4 * v + 3] * sigmoidf_(n3_ + 1.f) + accv[4 * v + 3];
      } else {
        ov[4 * v] = sigmoidf_(n0_); ov[4 * v + 1] = sigmoidf_(n1_);
        ov[4 * v + 2] = sigmoidf_(n2_); ov[4 * v + 3] = sigmoidf_(n3_);
      }
    }
  }

  float s = 0.f, ss = 0.f;
#pragma unroll
  for (int t = 0; t < 16; ++t) { s += accv[t]; ss += accv[t] * accv[t]; }
#pragma unroll
  for (int off = 32; off; off >>= 1) { s += __shfl_xor(s, off); ss += __shfl_xor(ss, off); }
  float mean = s * (1.f / 1024.f);
  float rstd = rsqrtf(ss * (1.f / 1024.f) - mean * mean + 1e-3f);

  const float4* cg4 = (const float4*)(cg + base);
  const float4* cb4 = (const float4*)(cb + base);
  float hv[16];
#pragma unroll
  for (int v = 0; v < 4; ++v) {
    float4 g4 = cg4[v], e4 = cb4[v];
    hv[4 * v]     = tanhf_((accv[4 * v]     - mean) * rstd * g4.x + e4.x) * ov[4 * v];
    hv[4 * v + 1] = tanhf_((accv[4 * v + 1] - mean) * rstd * g4.y + e4.y) * ov[4 * v + 1];
    hv[4 * v + 2] = tanhf_((accv[4 * v + 2] - mean) * rstd * g4.z + e4.z) * ov[4 * v + 2];
    hv[4 * v + 3] = tanhf_((accv[4 * v + 3] - mean) * rstd * g4.w + e4.w) * ov[4 * v + 3];
  }

  float4* oh = (float4*)(out + (size_t)row * Hdim + base);
  float4* oc = (float4*)(out + (size_t)Mdim * Hdim + (size_t)row * Hdim + base);
#pragma unroll
  for (int v = 0; v < 4; ++v) {
    oh[v] = make_float4(hv[4 * v], hv[4 * v + 1], hv[4 * v + 2], hv[4 * v + 3]);
    oc[v] = make_float4(accv[4 * v], accv[4 * v + 1], accv[4 * v + 2], accv[4 * v + 3]);
  }
}

extern "C" void kernel_launch(void* const* d_in, const int* in_sizes, int n_in,
                              void* d_out, int out_size, void* d_ws, size_t ws_size,
                              hipStream_t stream) {
  const float* x    = (const float*)d_in[0];
  const float* c    = (const float*)d_in[1];
  const float* h    = (const float*)d_in[2];
  const float* Wxh  = (const float*)d_in[3];
  const float* Whh  = (const float*)d_in[4];
  const float* bias = (const float*)d_in[5];
  const float* lng  = (const float*)d_in[6];
  const float* lnb  = (const float*)d_in[7];
  const float* cg   = (const float*)d_in[8];
  const float* cb   = (const float*)d_in[9];
  float* out = (float*)d_out;

  unsigned short* Abf = (unsigned short*)d_ws;                  // 32 MiB
  unsigned short* Wt  = Abf + (size_t)Mdim * Kdim;              // 16 MiB
  unsigned short* Cc  = Wt  + (size_t)Ndim * Kdim;              // 64 MiB

  pack_kernel<<<16384, 256, 0, stream>>>(x, h, Wxh, Whh, Abf, Wt);
  gemm_kernel<<<(Mdim / BM) * (Ndim / BN), 512, 0, stream>>>(Abf, Wt, Cc);
  tail_kernel<<<Mdim / 4, 256, 0, stream>>>(Cc, c, bias, lng, lnb, cg, cb, out);
}